// Round 10
// baseline (2563.937 us; speedup 1.0000x reference)
//
#include <hip/hip_runtime.h>
#include <math.h>

#define HH 512
#define VV 32000
#define BB 64
#define SS 64
#define TT 64
#define H3 1536

// ---- workspace layout (float offsets); everything below WS_HSALL is dead
// after the recurrence, so wbf (32000*512 ushort = 8,192,000 f) aliases it. ----
#define WS_GIEMBBF 0LL          // 4096*1536 ushort = 3,145,728 f
#define WS_UKBF    3145728LL    // 4096*512 ushort
#define WS_ENCBF   4194304LL    // 4096*512 ushort
#define WS_EMBBF   5242880LL    // 4096*512 ushort
#define WS_WCATBF  6291456LL    // 2048*512 ushort (rows 0..511 = Wa bf16)
#define WS_WIHC3   6815744LL    // 1536*512 ushort (rows j*3+g, ctx half of W_ih)
#define WS_WIHE    7208960LL    // 1536*512 ushort (emb half of W_ih)
#define WS_UABF    7602176LL    // 512*512 ushort
#define WS_WHH3    7733248LL    // 1536*512 ushort (rows j*3+g of W_hh)
#define WS_BCAT    8126464LL    // 2048 f
#define WS_CTXBF   8128512LL    // 64*512 ushort
#define WS_H32     8144896LL    // 2 x 64*512 f
#define WS_HBF     8210432LL    // 2 x 64*512 ushort
#define WS_HSALL   8388608LL    // 4096*512 ushort (rows b*T+t) -- LIVE after recurrence
// end 9,437,184 f = 37.7 MB

// output layout (floats)
#define OUT_HT  ((long long)BB*TT*VV)
#define OUT_ATT (OUT_HT + (long long)BB*HH)

typedef __attribute__((ext_vector_type(8))) short bf16x8;
typedef __attribute__((ext_vector_type(4))) float f32x4;

__device__ inline unsigned short f2b(float x) {
  unsigned u = __builtin_bit_cast(unsigned, x);
  unsigned r = (u + 0x7FFF + ((u >> 16) & 1)) >> 16;
  return (unsigned short)r;
}
__device__ inline float bc(unsigned u) { return __builtin_bit_cast(float, u); }
__device__ inline float b2f(unsigned short h) { return bc(((unsigned)h) << 16); }
__device__ inline float frcp(float x) { return __builtin_amdgcn_rcpf(x); }
__device__ inline float tanh_fast(float x) { return 1.f - 2.f * frcp(__expf(2.f * x) + 1.f); }
__device__ inline float sigm(float x) { return frcp(1.f + __expf(-x)); }

#define GLDS(gp, lp) __builtin_amdgcn_global_load_lds( \
    (const __attribute__((address_space(1))) void*)(gp), \
    (__attribute__((address_space(3))) void*)(lp), 16, 0, 0)

// ---------------------------------------------------------------------------
// prep kernels
// ---------------------------------------------------------------------------
__global__ __launch_bounds__(256) void build_wcat_kernel(const float* __restrict__ Wa,
    const float* __restrict__ Whh, const float* __restrict__ ba,
    const float* __restrict__ bhh, unsigned short* __restrict__ wcatbf,
    float* __restrict__ bcat)
{
  long long i = (long long)blockIdx.x * 256 + threadIdx.x;   // 2048*512
  int j = (int)(i >> 9), k = (int)(i & 511);
  float v = (j < HH) ? Wa[(long long)j*HH + k] : Whh[(long long)(j - HH)*HH + k];
  wcatbf[i] = f2b(v);
  if (i < 2048) bcat[i] = (i < HH) ? ba[i] : bhh[i - HH];
}

// o[(j*3+g)][k] = Wsrc[g*512+j][ofs+k]; Wsrc row stride = ld
__global__ __launch_bounds__(256) void build_g3_kernel(const float* __restrict__ Wsrc,
    unsigned short* __restrict__ o, int ld, int ofs)
{
  long long i = (long long)blockIdx.x * 256 + threadIdx.x;   // 1536*512
  int rp = (int)(i >> 9), k = (int)(i & 511);
  int j = rp / 3, g = rp - j * 3;
  o[i] = f2b(Wsrc[((long long)(g*512 + j))*ld + ofs + k]);
}

// wihebf[j][k] = W_ih[j][k]  (emb half)
__global__ __launch_bounds__(256) void build_wihe_kernel(const float* __restrict__ W_ih,
    unsigned short* __restrict__ o)
{
  long long i = (long long)blockIdx.x * 256 + threadIdx.x;   // 1536*512
  o[i] = f2b(W_ih[(long long)(i >> 9)*1024 + (i & 511)]);
}

__global__ __launch_bounds__(256) void cvt_f2b_kernel(const float* __restrict__ in,
    unsigned short* __restrict__ outp, long long n)
{
  long long i = ((long long)blockIdx.x * 256 + threadIdx.x) * 4;
  if (i >= n) return;
  float4 v = *(const float4*)(in + i);
  ushort4 r = { f2b(v.x), f2b(v.y), f2b(v.z), f2b(v.w) };
  *(ushort4*)(outp + i) = r;
}

// embbf row m = t*64+b  <-  emb[tok(b,t)]
__global__ __launch_bounds__(256) void build_embbf_kernel(const float* __restrict__ emb,
    const int* __restrict__ tgt, unsigned short* __restrict__ embbf)
{
  const int m = blockIdx.x, t = m >> 6, b = m & 63;
  const int tk = (t == 0) ? 0 : tgt[b*TT + t - 1];
  const float* src = emb + (long long)tk*HH;
  unsigned short* dst = embbf + (long long)m*HH;
  const int i = threadIdx.x;
  dst[i] = f2b(src[i]);
  dst[i + 256] = f2b(src[i + 256]);
}

__global__ __launch_bounds__(256) void hinit_kernel(const float* __restrict__ eh,
    unsigned short* __restrict__ hbf0, float* __restrict__ h320)
{
  int i = blockIdx.x * 256 + threadIdx.x;   // 32768
  float v = eh[i];
  hbf0[i] = f2b(v);
  h320[i] = v;
}

// ---------------------------------------------------------------------------
// Generic NT MFMA GEMM: C[m][n] = A[m,:512].B[n,:512] + bias[n]
// ---------------------------------------------------------------------------
template<int OUTBF>
__global__ __launch_bounds__(256) void mfma_nt(const unsigned short* __restrict__ A,
    const unsigned short* __restrict__ Bw, const float* __restrict__ bias,
    void* __restrict__ Cv, long long ldc)
{
  __shared__ unsigned short As[128*32];
  __shared__ unsigned short Bs[128*32];
  const int tid = threadIdx.x;
  const int w = tid >> 6, l = tid & 63;
  const int m0 = blockIdx.y * 128, n0 = blockIdx.x * 128;
  const int wr = w >> 1, wc = w & 1;

  f32x4 acc[4][4];
  #pragma unroll
  for (int i = 0; i < 4; i++)
    #pragma unroll
    for (int j = 0; j < 4; j++) acc[i][j] = (f32x4){0.f, 0.f, 0.f, 0.f};

  const int srow = l >> 2;
  const int scol = (l & 3) * 8;

  for (int k0 = 0; k0 < HH; k0 += 32) {
    __syncthreads();
    #pragma unroll
    for (int q = 0; q < 2; ++q) {
      int r = w*32 + q*16 + srow;
      GLDS(A  + (long long)(m0 + r)*HH + k0 + scol, As + r*32 + scol);
      GLDS(Bw + (long long)(n0 + r)*HH + k0 + scol, Bs + r*32 + scol);
    }
    __syncthreads();

    bf16x8 a[4], b[4];
    #pragma unroll
    for (int mi = 0; mi < 4; mi++)
      a[mi] = *(const bf16x8*)&As[(wr*64 + mi*16 + (l & 15))*32 + (l >> 4)*8];
    #pragma unroll
    for (int ni = 0; ni < 4; ni++)
      b[ni] = *(const bf16x8*)&Bs[(wc*64 + ni*16 + (l & 15))*32 + (l >> 4)*8];
    #pragma unroll
    for (int mi = 0; mi < 4; mi++)
      #pragma unroll
      for (int ni = 0; ni < 4; ni++)
        acc[mi][ni] = __builtin_amdgcn_mfma_f32_16x16x32_bf16(a[mi], b[ni], acc[mi][ni], 0, 0, 0);
  }

  #pragma unroll
  for (int mi = 0; mi < 4; mi++) {
    #pragma unroll
    for (int ni = 0; ni < 4; ni++) {
      int col = n0 + wc*64 + ni*16 + (l & 15);
      float bb = bias[col];
      #pragma unroll
      for (int r2 = 0; r2 < 4; r2++) {
        int row = m0 + wr*64 + mi*16 + (l >> 4)*4 + r2;
        float v = acc[mi][ni][r2] + bb;
        if (OUTBF) ((unsigned short*)Cv)[(long long)row*ldc + col] = f2b(v);
        else       ((float*)Cv)[(long long)row*ldc + col] = v;
      }
    }
  }
}

// ---------------------------------------------------------------------------
// K1: q via broadcast-row MFMA + attention. Grid 64 (b), 256 thr.
// q[c] = h[b]·Wa[c] + ba[c] computed in-block (Wa = wcatbf rows 0..511),
// then scores -> softmax -> ctx.
// ---------------------------------------------------------------------------
__global__ __launch_bounds__(256) void q_attn_kernel(int t,
    const unsigned short* __restrict__ hbf_r, const unsigned short* __restrict__ wabf,
    const float* __restrict__ bcat, const unsigned short* __restrict__ ukbf,
    const unsigned short* __restrict__ encbf, const float* __restrict__ Va,
    const float* __restrict__ bvp,
    unsigned short* __restrict__ ctxbf, float* __restrict__ attn_out)
{
  const int b = blockIdx.x, tid = threadIdx.x;
  const int w = tid >> 6, l = tid & 63;
  __shared__ unsigned short hsh[512];    // h[b]
  __shared__ unsigned short Ws[512*32];  // Wa k-slice (32 KB)
  __shared__ float qs2[8][68];
  __shared__ float vsh[8][68];
  __shared__ float sc[SS], sw[SS];

  ((unsigned*)hsh)[tid] = ((const unsigned*)(hbf_r + (long long)b*512))[tid];
  vsh[tid >> 6][tid & 63] = Va[tid];
  vsh[(tid + 256) >> 6][tid & 63] = Va[tid + 256];
  __syncthreads();

  // ---- q = h @ Wa^T : M=16 broadcast-row MFMA, wave w owns 8 n-tiles ----
  f32x4 acc[8];
  #pragma unroll
  for (int i = 0; i < 8; i++) acc[i] = (f32x4){0.f, 0.f, 0.f, 0.f};

  for (int k0 = 0; k0 < HH; k0 += 32) {
    if (k0) __syncthreads();
    #pragma unroll
    for (int q = 0; q < 8; ++q) {
      int idx = tid + q*256;                 // 0..2047
      int r = idx >> 2, c8 = (idx & 3) * 8;  // LDS byte off = 16*idx (lane-linear)
      GLDS(wabf + (long long)r*HH + k0 + c8, Ws + r*32 + c8);
    }
    __syncthreads();

    bf16x8 a = *(const bf16x8*)&hsh[k0 + (l >> 4)*8];   // broadcast rows
    #pragma unroll
    for (int i = 0; i < 8; ++i) {
      bf16x8 bfr = *(const bf16x8*)&Ws[(w*128 + i*16 + (l & 15))*32 + (l >> 4)*8];
      acc[i] = __builtin_amdgcn_mfma_f32_16x16x32_bf16(a, bfr, acc[i], 0, 0, 0);
    }
  }
  if (l < 16) {
    #pragma unroll
    for (int i = 0; i < 8; ++i) {
      int col = w*128 + i*16 + l;            // all C rows equal; take reg 0
      qs2[col >> 6][col & 63] = acc[i][0] + bcat[col];
    }
  }
  __syncthreads();

  // ---- scores: s = tid>>2, sub = tid&3, 128 k each (2 halves of 64) ----
  {
    const int s = tid >> 2, sub = tid & 3;
    float p_ = 0.f;
    #pragma unroll
    for (int half = 0; half < 2; ++half) {
      const int row = sub*2 + half;
      const uint4* up = (const uint4*)(ukbf + ((long long)(b*SS + s))*512 + row*64);
      const float* qp = &qs2[row][0];
      const float* vp = &vsh[row][0];
      #pragma unroll
      for (int i = 0; i < 8; ++i) {
        uint4 uv = up[i];
        int e = i*8;
        p_ = fmaf(vp[e+0], tanh_fast(qp[e+0] + bc(uv.x << 16)), p_);
        p_ = fmaf(vp[e+1], tanh_fast(qp[e+1] + bc(uv.x & 0xffff0000u)), p_);
        p_ = fmaf(vp[e+2], tanh_fast(qp[e+2] + bc(uv.y << 16)), p_);
        p_ = fmaf(vp[e+3], tanh_fast(qp[e+3] + bc(uv.y & 0xffff0000u)), p_);
        p_ = fmaf(vp[e+4], tanh_fast(qp[e+4] + bc(uv.z << 16)), p_);
        p_ = fmaf(vp[e+5], tanh_fast(qp[e+5] + bc(uv.z & 0xffff0000u)), p_);
        p_ = fmaf(vp[e+6], tanh_fast(qp[e+6] + bc(uv.w << 16)), p_);
        p_ = fmaf(vp[e+7], tanh_fast(qp[e+7] + bc(uv.w & 0xffff0000u)), p_);
      }
    }
    p_ += __shfl_xor(p_, 1);
    p_ += __shfl_xor(p_, 2);
    if (sub == 0) sc[s] = p_ + bvp[0];
  }
  __syncthreads();

  // ---- softmax over S=64 (wave 0) ----
  if (tid < 64) {
    float x = sc[tid], mx = x;
    #pragma unroll
    for (int off = 32; off; off >>= 1) mx = fmaxf(mx, __shfl_xor(mx, off));
    float e = __expf(x - mx), sm = e;
    #pragma unroll
    for (int off = 32; off; off >>= 1) sm += __shfl_xor(sm, off);
    float w_ = e * frcp(sm);
    sw[tid] = w_;
    attn_out[((long long)b*TT + t)*SS + tid] = w_;
  }
  __syncthreads();

  // ---- ctx[k] = sum_s sw[s] * enc[b][s][k]; 2 k per thread ----
  {
    float a0 = 0.f, a1 = 0.f;
    const unsigned short* ep = encbf + (long long)b*SS*512;
    #pragma unroll 8
    for (int s = 0; s < SS; ++s) {
      float w_ = sw[s];
      a0 = fmaf(w_, b2f(ep[s*512 + tid]), a0);
      a1 = fmaf(w_, b2f(ep[s*512 + tid + 256]), a1);
    }
    ctxbf[b*512 + tid]       = f2b(a0);
    ctxbf[b*512 + tid + 256] = f2b(a1);
  }
}

// ---------------------------------------------------------------------------
// K2: gh + gic (two gate-interleaved 64x96 MFMA GEMMs) + gates.
// grid 16 (j0 = blockIdx.x*32), 256 thr, waves 2x2 (32 rows x 48 cols).
// ---------------------------------------------------------------------------
__global__ __launch_bounds__(256) void ghgic_gates_mfma(int t,
    const unsigned short* __restrict__ hbf_r, const unsigned short* __restrict__ ctxbf,
    const unsigned short* __restrict__ wihc3bf, const unsigned short* __restrict__ whh3bf,
    const float* __restrict__ bcat, const unsigned short* __restrict__ giembbf,
    const float* __restrict__ h32_r, float* __restrict__ h32_w,
    unsigned short* __restrict__ hbf_w, unsigned short* __restrict__ hsall,
    float* __restrict__ out_ht)
{
  __shared__ unsigned short As[64*32];   // ctx tile
  __shared__ unsigned short Hs[64*32];   // h tile
  __shared__ unsigned short Bs[96*32];   // wihc3 rows
  __shared__ unsigned short Cs[96*32];   // whh3 rows
  __shared__ float gl[64*100];           // gic [64][96] padded
  __shared__ float hl[64*100];           // gh  [64][96] padded
  const int tid = threadIdx.x;
  const int w = tid >> 6, l = tid & 63;
  const int n0 = blockIdx.x * 96, j0 = blockIdx.x * 32;
  const int wr = w >> 1, wc = w & 1;

  f32x4 accg[2][3], acch[2][3];
  #pragma unroll
  for (int i = 0; i < 2; i++)
    #pragma unroll
    for (int j = 0; j < 3; j++) {
      accg[i][j] = (f32x4){0.f, 0.f, 0.f, 0.f};
      acch[i][j] = (f32x4){0.f, 0.f, 0.f, 0.f};
    }

  for (int k0 = 0; k0 < HH; k0 += 32) {
    __syncthreads();
    #pragma unroll
    for (int q = 0; q < 5; ++q) {
      int idx = tid + q*256;                    // 0..1279
      if (idx < 256) {
        int r = idx >> 2, c8 = (idx & 3) * 8;
        GLDS(ctxbf + (long long)r*HH + k0 + c8, As + r*32 + c8);
      } else if (idx < 512) {
        int i2 = idx - 256, r = i2 >> 2, c8 = (i2 & 3) * 8;
        GLDS(hbf_r + (long long)r*HH + k0 + c8, Hs + r*32 + c8);
      } else if (idx < 896) {
        int i2 = idx - 512, r = i2 >> 2, c8 = (i2 & 3) * 8;
        GLDS(wihc3bf + (long long)(n0 + r)*HH + k0 + c8, Bs + r*32 + c8);
      } else {
        int i2 = idx - 896, r = i2 >> 2, c8 = (i2 & 3) * 8;
        GLDS(whh3bf + (long long)(n0 + r)*HH + k0 + c8, Cs + r*32 + c8);
      }
    }
    __syncthreads();

    bf16x8 ag[2], ah[2], bg[3], bh[3];
    #pragma unroll
    for (int mi = 0; mi < 2; mi++) {
      ag[mi] = *(const bf16x8*)&As[(wr*32 + mi*16 + (l & 15))*32 + (l >> 4)*8];
      ah[mi] = *(const bf16x8*)&Hs[(wr*32 + mi*16 + (l & 15))*32 + (l >> 4)*8];
    }
    #pragma unroll
    for (int ni = 0; ni < 3; ni++) {
      bg[ni] = *(const bf16x8*)&Bs[(wc*48 + ni*16 + (l & 15))*32 + (l >> 4)*8];
      bh[ni] = *(const bf16x8*)&Cs[(wc*48 + ni*16 + (l & 15))*32 + (l >> 4)*8];
    }
    #pragma unroll
    for (int mi = 0; mi < 2; mi++)
      #pragma unroll
      for (int ni = 0; ni < 3; ni++) {
        accg[mi][ni] = __builtin_amdgcn_mfma_f32_16x16x32_bf16(ag[mi], bg[ni], accg[mi][ni], 0, 0, 0);
        acch[mi][ni] = __builtin_amdgcn_mfma_f32_16x16x32_bf16(ah[mi], bh[ni], acch[mi][ni], 0, 0, 0);
      }
  }

  #pragma unroll
  for (int mi = 0; mi < 2; mi++)
    #pragma unroll
    for (int ni = 0; ni < 3; ni++) {
      int col = wc*48 + ni*16 + (l & 15);
      #pragma unroll
      for (int r2 = 0; r2 < 4; r2++) {
        int row = wr*32 + mi*16 + (l >> 4)*4 + r2;
        gl[row*100 + col] = accg[mi][ni][r2];
        hl[row*100 + col] = acch[mi][ni][r2];
      }
    }
  __syncthreads();

  // gates: 2048 (b, jj) pairs
  for (int i = tid; i < 2048; i += 256) {
    const int b = i >> 5, jj = i & 31, j = j0 + jj;
    float gcr = gl[b*100 + jj*3 + 0];
    float gcz = gl[b*100 + jj*3 + 1];
    float gcn = gl[b*100 + jj*3 + 2];
    float ghr = hl[b*100 + jj*3 + 0] + bcat[512 + j];
    float ghz = hl[b*100 + jj*3 + 1] + bcat[1024 + j];
    float ghn = hl[b*100 + jj*3 + 2] + bcat[1536 + j];
    const long long gb = ((long long)t*BB + b)*H3 + j;
    float gir = b2f(giembbf[gb]);
    float giz = b2f(giembbf[gb + 512]);
    float gin = b2f(giembbf[gb + 1024]);
    float r = sigm(gir + gcr + ghr);
    float z = sigm(giz + gcz + ghz);
    float n = tanh_fast(gin + gcn + r * ghn);
    float hold = h32_r[b*512 + j];
    float hn = (1.f - z) * n + z * hold;
    h32_w[b*512 + j] = hn;
    unsigned short hb = f2b(hn);
    hbf_w[b*512 + j] = hb;
    hsall[((long long)b*TT + t)*512 + j] = hb;
    if (t == TT - 1) out_ht[b*512 + j] = hn;
  }
}

// ---------------------------------------------------------------------------
// In-place log-softmax over rows of V=32000, 1024 thr, float4
// ---------------------------------------------------------------------------
__global__ __launch_bounds__(1024) void logsoftmax_kernel(float* __restrict__ lp)
{
  float4* p4 = (float4*)(lp + (long long)blockIdx.x * VV);
  const int tid = threadIdx.x;
  float m = -1e30f, s = 0.f;
  for (int v = tid; v < 8000; v += 1024) {
    float4 x = p4[v];
    float mx = fmaxf(fmaxf(x.x, x.y), fmaxf(x.z, x.w));
    float e = __expf(x.x - mx) + __expf(x.y - mx) + __expf(x.z - mx) + __expf(x.w - mx);
    if (mx > m) { s = s * __expf(m - mx) + e; m = mx; }
    else        { s += e * __expf(mx - m); }
  }
  #pragma unroll
  for (int off = 32; off; off >>= 1) {
    float m2 = __shfl_xor(m, off), s2 = __shfl_xor(s, off);
    float mm = fmaxf(m, m2);
    s = s * __expf(m - mm) + s2 * __expf(m2 - mm);
    m = mm;
  }
  __shared__ float rm[16], rs[16];
  if ((tid & 63) == 0) { rm[tid >> 6] = m; rs[tid >> 6] = s; }
  __syncthreads();
  float M = rm[0], S = rs[0];
  #pragma unroll
  for (int i = 1; i < 16; ++i) {
    float m2 = rm[i], s2 = rs[i];
    float mm = fmaxf(M, m2);
    S = S * __expf(M - mm) + s2 * __expf(m2 - mm);
    M = mm;
  }
  const float L = M + logf(S);
  for (int v = tid; v < 8000; v += 1024) {
    float4 x = p4[v];
    x.x -= L; x.y -= L; x.z -= L; x.w -= L;
    p4[v] = x;
  }
}

// ---------------------------------------------------------------------------
extern "C" void kernel_launch(void* const* d_in, const int* in_sizes, int n_in,
                              void* d_out, int out_size, void* d_ws, size_t ws_size,
                              hipStream_t stream)
{
  const float* enc   = (const float*)d_in[0];
  const float* eh    = (const float*)d_in[1];
  const int*   tgt   = (const int*)  d_in[2];
  const float* emb   = (const float*)d_in[3];
  const float* Wa    = (const float*)d_in[4];
  const float* ba    = (const float*)d_in[5];
  const float* Ua    = (const float*)d_in[6];
  const float* bu    = (const float*)d_in[7];
  const float* Va    = (const float*)d_in[8];
  const float* bvp   = (const float*)d_in[9];
  const float* W_ih  = (const float*)d_in[10];
  const float* W_hh  = (const float*)d_in[11];
  const float* b_ih  = (const float*)d_in[12];
  const float* b_hh  = (const float*)d_in[13];
  const float* W_out = (const float*)d_in[14];
  const float* b_out = (const float*)d_in[15];

  float* out = (float*)d_out;
  float* ws  = (float*)d_ws;

  unsigned short* giembbf = (unsigned short*)(ws + WS_GIEMBBF);
  unsigned short* ukbf    = (unsigned short*)(ws + WS_UKBF);
  unsigned short* encbf   = (unsigned short*)(ws + WS_ENCBF);
  unsigned short* embbf   = (unsigned short*)(ws + WS_EMBBF);
  unsigned short* wcatbf  = (unsigned short*)(ws + WS_WCATBF);
  unsigned short* wihc3bf = (unsigned short*)(ws + WS_WIHC3);
  unsigned short* wihebf  = (unsigned short*)(ws + WS_WIHE);
  unsigned short* uabf    = (unsigned short*)(ws + WS_UABF);
  unsigned short* whh3bf  = (unsigned short*)(ws + WS_WHH3);
  float* bcat = ws + WS_BCAT;
  unsigned short* ctxbf = (unsigned short*)(ws + WS_CTXBF);
  float* h320 = ws + WS_H32;
  float* h321 = h320 + BB*HH;
  unsigned short* hbf0 = (unsigned short*)(ws + WS_HBF);
  unsigned short* hbf1 = hbf0 + BB*HH;
  unsigned short* hsall = (unsigned short*)(ws + WS_HSALL);
  unsigned short* wbf   = (unsigned short*)ws;   // aliases dead region post-recurrence

  float* attn_out = out + OUT_ATT;
  float* out_ht   = out + OUT_HT;

  // ---- prep ----
  build_wcat_kernel<<<dim3(4096), dim3(256), 0, stream>>>(Wa, W_hh, ba, b_hh, wcatbf, bcat);
  build_g3_kernel<<<dim3(3072), dim3(256), 0, stream>>>(W_ih, wihc3bf, 1024, 512);
  build_g3_kernel<<<dim3(3072), dim3(256), 0, stream>>>(W_hh, whh3bf, 512, 0);
  build_wihe_kernel<<<dim3(3072), dim3(256), 0, stream>>>(W_ih, wihebf);
  cvt_f2b_kernel<<<dim3(256), dim3(256), 0, stream>>>(Ua, uabf, (long long)HH*HH);
  cvt_f2b_kernel<<<dim3(2048), dim3(256), 0, stream>>>(enc, encbf, (long long)BB*SS*HH);
  build_embbf_kernel<<<dim3(4096), dim3(256), 0, stream>>>(emb, tgt, embbf);
  hinit_kernel<<<dim3(128), dim3(256), 0, stream>>>(eh, hbf0, h320);

  // Uk (bf16 out) and GiEmb (bf16 out) via MFMA
  mfma_nt<1><<<dim3(4, 32), dim3(256), 0, stream>>>(encbf, uabf, bu, (void*)ukbf, (long long)HH);
  mfma_nt<1><<<dim3(12, 32), dim3(256), 0, stream>>>(embbf, wihebf, b_ih, (void*)giembbf, (long long)H3);

  // ---- recurrence: 2 launches/step ----
  for (int t = 0; t < TT; ++t) {
    const unsigned short* hr  = (t & 1) ? hbf1 : hbf0;
    const float*          h32r = (t & 1) ? h321 : h320;
    unsigned short*       hw  = (t & 1) ? hbf0 : hbf1;
    float*                h32w = (t & 1) ? h320 : h321;
    q_attn_kernel<<<dim3(64), dim3(256), 0, stream>>>(t, hr, wcatbf, bcat,
        ukbf, encbf, Va, bvp, ctxbf, attn_out);
    ghgic_gates_mfma<<<dim3(16), dim3(256), 0, stream>>>(t, hr, ctxbf, wihc3bf, whh3bf,
        bcat, giembbf, h32r, h32w, hw, hsall, out_ht);
  }

  // ---- output projection + log-softmax ----
  cvt_f2b_kernel<<<dim3(16000), dim3(256), 0, stream>>>(W_out, wbf, (long long)VV*HH);
  mfma_nt<0><<<dim3(250, 32), dim3(256), 0, stream>>>(hsall, wbf, b_out, (void*)out, (long long)VV);
  logsoftmax_kernel<<<dim3(4096), dim3(1024), 0, stream>>>(out);
}

// Round 11
// 2182.785 us; speedup vs baseline: 1.1746x; 1.1746x over previous
//
#include <hip/hip_runtime.h>
#include <math.h>

#define HH 512
#define VV 32000
#define BB 64
#define SS 64
#define TT 64
#define H3 1536

// ---- workspace layout (float offsets); everything below WS_HSALL is dead
// after the recurrence, so wbf (32000*512 ushort = 8,192,000 f) aliases [0,8192000). ----
#define WS_GIEMBBF 0LL          // 4096*1536 ushort
#define WS_UKBF    3145728LL    // 4096*512 ushort
#define WS_ENCBF   4194304LL    // 4096*512 ushort
#define WS_EMBBF   5242880LL    // 4096*512 ushort
#define WS_WCATBF  6291456LL    // 2048*512 ushort (rows 0..511 = Wa bf16)
#define WS_WIHC3   6815744LL    // 1536*512 ushort (rows j*3+g, ctx half of W_ih)
#define WS_WIHE    7208960LL    // 1536*512 ushort (emb half of W_ih)
#define WS_UABF    7602176LL    // 512*512 ushort
#define WS_WHH3    7733248LL    // 1536*512 ushort (rows j*3+g of W_hh)
#define WS_BCAT    8126464LL    // 2048 f
#define WS_QBUF    8128512LL    // 64*512 f   (q for t=0, no bias)
#define WS_QPART   8161280LL    // 16*64*512 f (q partials)
#define WS_CTXBF   8685568LL    // 64*512 ushort
#define WS_H32     8701952LL    // 2 x 64*512 f
#define WS_HBF     8767488LL    // 2 x 64*512 ushort
#define WS_HSALL   8800256LL    // 4096*512 ushort (rows b*T+t) -- LIVE after recurrence
// end 9,848,832 f = 39.4 MB

// output layout (floats)
#define OUT_HT  ((long long)BB*TT*VV)
#define OUT_ATT (OUT_HT + (long long)BB*HH)

typedef __attribute__((ext_vector_type(8))) short bf16x8;
typedef __attribute__((ext_vector_type(4))) float f32x4;

__device__ inline unsigned short f2b(float x) {
  unsigned u = __builtin_bit_cast(unsigned, x);
  unsigned r = (u + 0x7FFF + ((u >> 16) & 1)) >> 16;
  return (unsigned short)r;
}
__device__ inline float bc(unsigned u) { return __builtin_bit_cast(float, u); }
__device__ inline float b2f(unsigned short h) { return bc(((unsigned)h) << 16); }
__device__ inline float frcp(float x) { return __builtin_amdgcn_rcpf(x); }
__device__ inline float tanh_fast(float x) { return 1.f - 2.f * frcp(__expf(2.f * x) + 1.f); }
__device__ inline float sigm(float x) { return frcp(1.f + __expf(-x)); }

#define GLDS(gp, lp) __builtin_amdgcn_global_load_lds( \
    (const __attribute__((address_space(1))) void*)(gp), \
    (__attribute__((address_space(3))) void*)(lp), 16, 0, 0)

// ---------------------------------------------------------------------------
// prep kernels
// ---------------------------------------------------------------------------
__global__ __launch_bounds__(256) void build_wcat_kernel(const float* __restrict__ Wa,
    const float* __restrict__ Whh, const float* __restrict__ ba,
    const float* __restrict__ bhh, unsigned short* __restrict__ wcatbf,
    float* __restrict__ bcat)
{
  long long i = (long long)blockIdx.x * 256 + threadIdx.x;   // 2048*512
  int j = (int)(i >> 9), k = (int)(i & 511);
  float v = (j < HH) ? Wa[(long long)j*HH + k] : Whh[(long long)(j - HH)*HH + k];
  wcatbf[i] = f2b(v);
  if (i < 2048) bcat[i] = (i < HH) ? ba[i] : bhh[i - HH];
}

// o[(j*3+g)][k] = Wsrc[g*512+j][ofs+k]; Wsrc row stride = ld
__global__ __launch_bounds__(256) void build_g3_kernel(const float* __restrict__ Wsrc,
    unsigned short* __restrict__ o, int ld, int ofs)
{
  long long i = (long long)blockIdx.x * 256 + threadIdx.x;   // 1536*512
  int rp = (int)(i >> 9), k = (int)(i & 511);
  int j = rp / 3, g = rp - j * 3;
  o[i] = f2b(Wsrc[((long long)(g*512 + j))*ld + ofs + k]);
}

// wihebf[j][k] = W_ih[j][k]  (emb half)
__global__ __launch_bounds__(256) void build_wihe_kernel(const float* __restrict__ W_ih,
    unsigned short* __restrict__ o)
{
  long long i = (long long)blockIdx.x * 256 + threadIdx.x;   // 1536*512
  o[i] = f2b(W_ih[(long long)(i >> 9)*1024 + (i & 511)]);
}

__global__ __launch_bounds__(256) void cvt_f2b_kernel(const float* __restrict__ in,
    unsigned short* __restrict__ outp, long long n)
{
  long long i = ((long long)blockIdx.x * 256 + threadIdx.x) * 4;
  if (i >= n) return;
  float4 v = *(const float4*)(in + i);
  ushort4 r = { f2b(v.x), f2b(v.y), f2b(v.z), f2b(v.w) };
  *(ushort4*)(outp + i) = r;
}

// embbf row m = t*64+b  <-  emb[tok(b,t)]
__global__ __launch_bounds__(256) void build_embbf_kernel(const float* __restrict__ emb,
    const int* __restrict__ tgt, unsigned short* __restrict__ embbf)
{
  const int m = blockIdx.x, t = m >> 6, b = m & 63;
  const int tk = (t == 0) ? 0 : tgt[b*TT + t - 1];
  const float* src = emb + (long long)tk*HH;
  unsigned short* dst = embbf + (long long)m*HH;
  const int i = threadIdx.x;
  dst[i] = f2b(src[i]);
  dst[i + 256] = f2b(src[i + 256]);
}

__global__ __launch_bounds__(256) void hinit_kernel(const float* __restrict__ eh,
    unsigned short* __restrict__ hbf0, float* __restrict__ h320)
{
  int i = blockIdx.x * 256 + threadIdx.x;   // 32768
  float v = eh[i];
  hbf0[i] = f2b(v);
  h320[i] = v;
}

// ---------------------------------------------------------------------------
// Generic NT MFMA GEMM: C[m][n] = A[m,:512].B[n,:512] + bias[n]
// ---------------------------------------------------------------------------
template<int OUTBF>
__global__ __launch_bounds__(256) void mfma_nt(const unsigned short* __restrict__ A,
    const unsigned short* __restrict__ Bw, const float* __restrict__ bias,
    void* __restrict__ Cv, long long ldc)
{
  __shared__ unsigned short As[128*32];
  __shared__ unsigned short Bs[128*32];
  const int tid = threadIdx.x;
  const int w = tid >> 6, l = tid & 63;
  const int m0 = blockIdx.y * 128, n0 = blockIdx.x * 128;
  const int wr = w >> 1, wc = w & 1;

  f32x4 acc[4][4];
  #pragma unroll
  for (int i = 0; i < 4; i++)
    #pragma unroll
    for (int j = 0; j < 4; j++) acc[i][j] = (f32x4){0.f, 0.f, 0.f, 0.f};

  const int srow = l >> 2;
  const int scol = (l & 3) * 8;

  for (int k0 = 0; k0 < HH; k0 += 32) {
    __syncthreads();
    #pragma unroll
    for (int q = 0; q < 2; ++q) {
      int r = w*32 + q*16 + srow;
      GLDS(A  + (long long)(m0 + r)*HH + k0 + scol, As + r*32 + scol);
      GLDS(Bw + (long long)(n0 + r)*HH + k0 + scol, Bs + r*32 + scol);
    }
    __syncthreads();

    bf16x8 a[4], b[4];
    #pragma unroll
    for (int mi = 0; mi < 4; mi++)
      a[mi] = *(const bf16x8*)&As[(wr*64 + mi*16 + (l & 15))*32 + (l >> 4)*8];
    #pragma unroll
    for (int ni = 0; ni < 4; ni++)
      b[ni] = *(const bf16x8*)&Bs[(wc*64 + ni*16 + (l & 15))*32 + (l >> 4)*8];
    #pragma unroll
    for (int mi = 0; mi < 4; mi++)
      #pragma unroll
      for (int ni = 0; ni < 4; ni++)
        acc[mi][ni] = __builtin_amdgcn_mfma_f32_16x16x32_bf16(a[mi], b[ni], acc[mi][ni], 0, 0, 0);
  }

  #pragma unroll
  for (int mi = 0; mi < 4; mi++) {
    #pragma unroll
    for (int ni = 0; ni < 4; ni++) {
      int col = n0 + wc*64 + ni*16 + (l & 15);
      float bb = bias[col];
      #pragma unroll
      for (int r2 = 0; r2 < 4; r2++) {
        int row = m0 + wr*64 + mi*16 + (l >> 4)*4 + r2;
        float v = acc[mi][ni][r2] + bb;
        if (OUTBF) ((unsigned short*)Cv)[(long long)row*ldc + col] = f2b(v);
        else       ((float*)Cv)[(long long)row*ldc + col] = v;
      }
    }
  }
}

// ---------------------------------------------------------------------------
// qinit: qbuf[64][512] = h0 @ Wa^T (no bias). grid 4, 256 thr (R9 qgh shape).
// ---------------------------------------------------------------------------
__global__ __launch_bounds__(256) void qinit_mfma(
    const unsigned short* __restrict__ hbf_r, const unsigned short* __restrict__ wabf,
    float* __restrict__ qbuf)
{
  __shared__ unsigned short As[64*32];
  __shared__ unsigned short Bs[128*32];
  const int tid = threadIdx.x;
  const int w = tid >> 6, l = tid & 63;
  const int n0 = blockIdx.x * 128;
  const int wr = w >> 1, wc = w & 1;

  f32x4 acc[2][4];
  #pragma unroll
  for (int i = 0; i < 2; i++)
    #pragma unroll
    for (int j = 0; j < 4; j++) acc[i][j] = (f32x4){0.f, 0.f, 0.f, 0.f};

  const int ar = tid >> 2;
  const int ac8 = (tid & 3) * 8;

  for (int k0 = 0; k0 < HH; k0 += 32) {
    __syncthreads();
    GLDS(hbf_r + (long long)ar*HH + k0 + ac8, As + ar*32 + ac8);
    #pragma unroll
    for (int q = 0; q < 2; ++q) {
      int r = q*64 + ar;
      GLDS(wabf + (long long)(n0 + r)*HH + k0 + ac8, Bs + r*32 + ac8);
    }
    __syncthreads();

    bf16x8 a[2], b[4];
    #pragma unroll
    for (int mi = 0; mi < 2; mi++)
      a[mi] = *(const bf16x8*)&As[(wr*32 + mi*16 + (l & 15))*32 + (l >> 4)*8];
    #pragma unroll
    for (int ni = 0; ni < 4; ni++)
      b[ni] = *(const bf16x8*)&Bs[(wc*64 + ni*16 + (l & 15))*32 + (l >> 4)*8];
    #pragma unroll
    for (int mi = 0; mi < 2; mi++)
      #pragma unroll
      for (int ni = 0; ni < 4; ni++)
        acc[mi][ni] = __builtin_amdgcn_mfma_f32_16x16x32_bf16(a[mi], b[ni], acc[mi][ni], 0, 0, 0);
  }

  #pragma unroll
  for (int mi = 0; mi < 2; mi++) {
    #pragma unroll
    for (int ni = 0; ni < 4; ni++) {
      int col = n0 + wc*64 + ni*16 + (l & 15);
      #pragma unroll
      for (int r2 = 0; r2 < 4; r2++) {
        int row = wr*32 + mi*16 + (l >> 4)*4 + r2;
        qbuf[(long long)row*512 + col] = acc[mi][ni][r2];
      }
    }
  }
}

// ---------------------------------------------------------------------------
// attn for batch b = blockIdx.x, 512 thr. q = bcat + (qbuf | sum of 16 qPart).
// ---------------------------------------------------------------------------
__global__ __launch_bounds__(512) void attn_kernel(int t, int first,
    const float* __restrict__ qbuf, const float* __restrict__ qPart,
    const float* __restrict__ bcat, const unsigned short* __restrict__ ukbf,
    const unsigned short* __restrict__ encbf, const float* __restrict__ Va,
    const float* __restrict__ bvp,
    unsigned short* __restrict__ ctxbf, float* __restrict__ attn_out)
{
  const int b = blockIdx.x, tid = threadIdx.x;
  __shared__ float qs2[8][68];
  __shared__ float vsh[8][68];
  __shared__ float sc[SS], sw[SS];

  {
    const int c = tid;
    float q = bcat[c];
    if (first) {
      q += qbuf[(long long)b*512 + c];
    } else {
      #pragma unroll
      for (int i = 0; i < 16; ++i)
        q += qPart[(long long)i*32768 + b*512 + c];
    }
    qs2[c >> 6][c & 63] = q;
    vsh[c >> 6][c & 63] = Va[c];
  }
  __syncthreads();

  // scores: (s = tid>>3, sub = tid&7), 64 k each
  {
    const int s = tid >> 3, sub = tid & 7;
    const uint4* up = (const uint4*)(ukbf + ((long long)(b*SS + s))*512 + sub*64);
    const float* qp = &qs2[sub][0];
    const float* vp = &vsh[sub][0];
    float p_ = 0.f;
    #pragma unroll
    for (int i = 0; i < 8; ++i) {
      uint4 uv = up[i];
      int e = i*8;
      p_ = fmaf(vp[e+0], tanh_fast(qp[e+0] + bc(uv.x << 16)), p_);
      p_ = fmaf(vp[e+1], tanh_fast(qp[e+1] + bc(uv.x & 0xffff0000u)), p_);
      p_ = fmaf(vp[e+2], tanh_fast(qp[e+2] + bc(uv.y << 16)), p_);
      p_ = fmaf(vp[e+3], tanh_fast(qp[e+3] + bc(uv.y & 0xffff0000u)), p_);
      p_ = fmaf(vp[e+4], tanh_fast(qp[e+4] + bc(uv.z << 16)), p_);
      p_ = fmaf(vp[e+5], tanh_fast(qp[e+5] + bc(uv.z & 0xffff0000u)), p_);
      p_ = fmaf(vp[e+6], tanh_fast(qp[e+6] + bc(uv.w << 16)), p_);
      p_ = fmaf(vp[e+7], tanh_fast(qp[e+7] + bc(uv.w & 0xffff0000u)), p_);
    }
    p_ += __shfl_xor(p_, 1);
    p_ += __shfl_xor(p_, 2);
    p_ += __shfl_xor(p_, 4);
    if (sub == 0) sc[s] = p_ + bvp[0];
  }
  __syncthreads();

  if (tid < 64) {
    float x = sc[tid], mx = x;
    #pragma unroll
    for (int off = 32; off; off >>= 1) mx = fmaxf(mx, __shfl_xor(mx, off));
    float e = __expf(x - mx), sm = e;
    #pragma unroll
    for (int off = 32; off; off >>= 1) sm += __shfl_xor(sm, off);
    float w_ = e * frcp(sm);
    sw[tid] = w_;
    attn_out[((long long)b*TT + t)*SS + tid] = w_;
  }
  __syncthreads();

  {
    float a = 0.f;
    const unsigned short* ep = encbf + (long long)b*SS*512 + tid;
    #pragma unroll 8
    for (int s = 0; s < SS; ++s)
      a = fmaf(sw[s], b2f(ep[s*512]), a);
    ctxbf[b*512 + tid] = f2b(a);
  }
}

// ---------------------------------------------------------------------------
// gates_qgh: gh + gic (two gate-interleaved 64x96 MFMA GEMMs) + gates + h,
// then q-partial for step t+1: qPart[bid] = h_new[:, kslice] @ Wa[:, kslice]^T.
// grid 16 (j0 = kslice = blockIdx.x*32), 256 thr.
// ---------------------------------------------------------------------------
__global__ __launch_bounds__(256) void gates_qgh_mfma(int t, int last,
    const unsigned short* __restrict__ hbf_r, const unsigned short* __restrict__ ctxbf,
    const unsigned short* __restrict__ wihc3bf, const unsigned short* __restrict__ whh3bf,
    const unsigned short* __restrict__ wabf, const float* __restrict__ bcat,
    const unsigned short* __restrict__ giembbf,
    const float* __restrict__ h32_r, float* __restrict__ h32_w,
    unsigned short* __restrict__ hbf_w, unsigned short* __restrict__ hsall,
    float* __restrict__ out_ht, float* __restrict__ qPart)
{
  __shared__ unsigned short As[64*32];   // ctx tile
  __shared__ unsigned short Hs[64*32];   // h tile
  __shared__ unsigned short Bs[96*32];   // wihc3 rows
  __shared__ unsigned short Cs[96*32];   // whh3 rows
  __shared__ unsigned short Was[512*32]; // Wa k-slice (all 512 rows x 32 k)
  __shared__ unsigned short hnewp[64*40];// h_new slice, padded rows
  __shared__ float gl[64*100];           // gic [64][96] padded
  __shared__ float hl[64*100];           // gh  [64][96] padded
  const int tid = threadIdx.x;
  const int w = tid >> 6, l = tid & 63;
  const int n0 = blockIdx.x * 96, j0 = blockIdx.x * 32;
  const int wr = w >> 1, wc = w & 1;

  f32x4 accg[2][3], acch[2][3];
  #pragma unroll
  for (int i = 0; i < 2; i++)
    #pragma unroll
    for (int j = 0; j < 3; j++) {
      accg[i][j] = (f32x4){0.f, 0.f, 0.f, 0.f};
      acch[i][j] = (f32x4){0.f, 0.f, 0.f, 0.f};
    }

  for (int k0 = 0; k0 < HH; k0 += 32) {
    __syncthreads();
    #pragma unroll
    for (int q = 0; q < 5; ++q) {
      int idx = tid + q*256;                    // 0..1279
      if (idx < 256) {
        int r = idx >> 2, c8 = (idx & 3) * 8;
        GLDS(ctxbf + (long long)r*HH + k0 + c8, As + r*32 + c8);
      } else if (idx < 512) {
        int i2 = idx - 256, r = i2 >> 2, c8 = (i2 & 3) * 8;
        GLDS(hbf_r + (long long)r*HH + k0 + c8, Hs + r*32 + c8);
      } else if (idx < 896) {
        int i2 = idx - 512, r = i2 >> 2, c8 = (i2 & 3) * 8;
        GLDS(wihc3bf + (long long)(n0 + r)*HH + k0 + c8, Bs + r*32 + c8);
      } else {
        int i2 = idx - 896, r = i2 >> 2, c8 = (i2 & 3) * 8;
        GLDS(whh3bf + (long long)(n0 + r)*HH + k0 + c8, Cs + r*32 + c8);
      }
    }
    __syncthreads();

    bf16x8 ag[2], ah[2], bg[3], bh[3];
    #pragma unroll
    for (int mi = 0; mi < 2; mi++) {
      ag[mi] = *(const bf16x8*)&As[(wr*32 + mi*16 + (l & 15))*32 + (l >> 4)*8];
      ah[mi] = *(const bf16x8*)&Hs[(wr*32 + mi*16 + (l & 15))*32 + (l >> 4)*8];
    }
    #pragma unroll
    for (int ni = 0; ni < 3; ni++) {
      bg[ni] = *(const bf16x8*)&Bs[(wc*48 + ni*16 + (l & 15))*32 + (l >> 4)*8];
      bh[ni] = *(const bf16x8*)&Cs[(wc*48 + ni*16 + (l & 15))*32 + (l >> 4)*8];
    }
    #pragma unroll
    for (int mi = 0; mi < 2; mi++)
      #pragma unroll
      for (int ni = 0; ni < 3; ni++) {
        accg[mi][ni] = __builtin_amdgcn_mfma_f32_16x16x32_bf16(ag[mi], bg[ni], accg[mi][ni], 0, 0, 0);
        acch[mi][ni] = __builtin_amdgcn_mfma_f32_16x16x32_bf16(ah[mi], bh[ni], acch[mi][ni], 0, 0, 0);
      }
  }

  // prefetch Wa k-slice for the q-partial pass (overlaps gl/hl + gates)
  if (!last) {
    #pragma unroll
    for (int q = 0; q < 8; ++q) {
      int idx = tid + q*256;                    // 0..2047
      int r = idx >> 2, c8 = (idx & 3) * 8;
      GLDS(wabf + (long long)r*HH + j0 + c8, Was + r*32 + c8);
    }
  }

  #pragma unroll
  for (int mi = 0; mi < 2; mi++)
    #pragma unroll
    for (int ni = 0; ni < 3; ni++) {
      int col = wc*48 + ni*16 + (l & 15);
      #pragma unroll
      for (int r2 = 0; r2 < 4; r2++) {
        int row = wr*32 + mi*16 + (l >> 4)*4 + r2;
        gl[row*100 + col] = accg[mi][ni][r2];
        hl[row*100 + col] = acch[mi][ni][r2];
      }
    }
  __syncthreads();

  // gates: 2048 (b, jj) pairs -> h_new
  for (int i = tid; i < 2048; i += 256) {
    const int b = i >> 5, jj = i & 31, j = j0 + jj;
    float gcr = gl[b*100 + jj*3 + 0];
    float gcz = gl[b*100 + jj*3 + 1];
    float gcn = gl[b*100 + jj*3 + 2];
    float ghr = hl[b*100 + jj*3 + 0] + bcat[512 + j];
    float ghz = hl[b*100 + jj*3 + 1] + bcat[1024 + j];
    float ghn = hl[b*100 + jj*3 + 2] + bcat[1536 + j];
    const long long gb = ((long long)t*BB + b)*H3 + j;
    float gir = b2f(giembbf[gb]);
    float giz = b2f(giembbf[gb + 512]);
    float gin = b2f(giembbf[gb + 1024]);
    float r = sigm(gir + gcr + ghr);
    float z = sigm(giz + gcz + ghz);
    float n = tanh_fast(gin + gcn + r * ghn);
    float hold = h32_r[b*512 + j];
    float hn = (1.f - z) * n + z * hold;
    h32_w[b*512 + j] = hn;
    unsigned short hb = f2b(hn);
    hbf_w[b*512 + j] = hb;
    hsall[((long long)b*TT + t)*512 + j] = hb;
    hnewp[b*40 + jj] = hb;
    if (t == TT - 1) out_ht[b*512 + j] = hn;
  }
  __syncthreads();

  // q-partial: qPart[bid][b][n] = h_new[b][kslice] . Wa[n][kslice]  (K=32, one MFMA)
  if (!last) {
    f32x4 qa[4][8];
    #pragma unroll
    for (int mi = 0; mi < 4; mi++)
      #pragma unroll
      for (int ni = 0; ni < 8; ni++) qa[mi][ni] = (f32x4){0.f, 0.f, 0.f, 0.f};

    bf16x8 a[4];
    #pragma unroll
    for (int mi = 0; mi < 4; mi++)
      a[mi] = *(const bf16x8*)&hnewp[(mi*16 + (l & 15))*40 + (l >> 4)*8];
    #pragma unroll
    for (int ni = 0; ni < 8; ni++) {
      bf16x8 bfr = *(const bf16x8*)&Was[(w*128 + ni*16 + (l & 15))*32 + (l >> 4)*8];
      #pragma unroll
      for (int mi = 0; mi < 4; mi++)
        qa[mi][ni] = __builtin_amdgcn_mfma_f32_16x16x32_bf16(a[mi], bfr, qa[mi][ni], 0, 0, 0);
    }

    float* qp = qPart + (long long)blockIdx.x * 32768;
    #pragma unroll
    for (int mi = 0; mi < 4; mi++)
      #pragma unroll
      for (int ni = 0; ni < 8; ni++) {
        int col = w*128 + ni*16 + (l & 15);
        #pragma unroll
        for (int r2 = 0; r2 < 4; r2++) {
          int row = mi*16 + (l >> 4)*4 + r2;
          qp[row*512 + col] = qa[mi][ni][r2];
        }
      }
  }
}

// ---------------------------------------------------------------------------
// In-place log-softmax over rows of V=32000, 1024 thr, float4
// ---------------------------------------------------------------------------
__global__ __launch_bounds__(1024) void logsoftmax_kernel(float* __restrict__ lp)
{
  float4* p4 = (float4*)(lp + (long long)blockIdx.x * VV);
  const int tid = threadIdx.x;
  float m = -1e30f, s = 0.f;
  for (int v = tid; v < 8000; v += 1024) {
    float4 x = p4[v];
    float mx = fmaxf(fmaxf(x.x, x.y), fmaxf(x.z, x.w));
    float e = __expf(x.x - mx) + __expf(x.y - mx) + __expf(x.z - mx) + __expf(x.w - mx);
    if (mx > m) { s = s * __expf(m - mx) + e; m = mx; }
    else        { s += e * __expf(mx - m); }
  }
  #pragma unroll
  for (int off = 32; off; off >>= 1) {
    float m2 = __shfl_xor(m, off), s2 = __shfl_xor(s, off);
    float mm = fmaxf(m, m2);
    s = s * __expf(m - mm) + s2 * __expf(m2 - mm);
    m = mm;
  }
  __shared__ float rm[16], rs[16];
  if ((tid & 63) == 0) { rm[tid >> 6] = m; rs[tid >> 6] = s; }
  __syncthreads();
  float M = rm[0], S = rs[0];
  #pragma unroll
  for (int i = 1; i < 16; ++i) {
    float m2 = rm[i], s2 = rs[i];
    float mm = fmaxf(M, m2);
    S = S * __expf(M - mm) + s2 * __expf(m2 - mm);
    M = mm;
  }
  const float L = M + logf(S);
  for (int v = tid; v < 8000; v += 1024) {
    float4 x = p4[v];
    x.x -= L; x.y -= L; x.z -= L; x.w -= L;
    p4[v] = x;
  }
}

// ---------------------------------------------------------------------------
extern "C" void kernel_launch(void* const* d_in, const int* in_sizes, int n_in,
                              void* d_out, int out_size, void* d_ws, size_t ws_size,
                              hipStream_t stream)
{
  const float* enc   = (const float*)d_in[0];
  const float* eh    = (const float*)d_in[1];
  const int*   tgt   = (const int*)  d_in[2];
  const float* emb   = (const float*)d_in[3];
  const float* Wa    = (const float*)d_in[4];
  const float* ba    = (const float*)d_in[5];
  const float* Ua    = (const float*)d_in[6];
  const float* bu    = (const float*)d_in[7];
  const float* Va    = (const float*)d_in[8];
  const float* bvp   = (const float*)d_in[9];
  const float* W_ih  = (const float*)d_in[10];
  const float* W_hh  = (const float*)d_in[11];
  const float* b_ih  = (const float*)d_in[12];
  const float* b_hh  = (const float*)d_in[13];
  const float* W_out = (const float*)d_in[14];
  const float* b_out = (const float*)d_in[15];

  float* out = (float*)d_out;
  float* ws  = (float*)d_ws;

  unsigned short* giembbf = (unsigned short*)(ws + WS_GIEMBBF);
  unsigned short* ukbf    = (unsigned short*)(ws + WS_UKBF);
  unsigned short* encbf   = (unsigned short*)(ws + WS_ENCBF);
  unsigned short* embbf   = (unsigned short*)(ws + WS_EMBBF);
  unsigned short* wcatbf  = (unsigned short*)(ws + WS_WCATBF);
  unsigned short* wihc3bf = (unsigned short*)(ws + WS_WIHC3);
  unsigned short* wihebf  = (unsigned short*)(ws + WS_WIHE);
  unsigned short* uabf    = (unsigned short*)(ws + WS_UABF);
  unsigned short* whh3bf  = (unsigned short*)(ws + WS_WHH3);
  float* bcat  = ws + WS_BCAT;
  float* qbuf  = ws + WS_QBUF;
  float* qPart = ws + WS_QPART;
  unsigned short* ctxbf = (unsigned short*)(ws + WS_CTXBF);
  float* h320 = ws + WS_H32;
  float* h321 = h320 + BB*HH;
  unsigned short* hbf0 = (unsigned short*)(ws + WS_HBF);
  unsigned short* hbf1 = hbf0 + BB*HH;
  unsigned short* hsall = (unsigned short*)(ws + WS_HSALL);
  unsigned short* wbf   = (unsigned short*)ws;   // aliases dead region post-recurrence

  float* attn_out = out + OUT_ATT;
  float* out_ht   = out + OUT_HT;

  // ---- prep ----
  build_wcat_kernel<<<dim3(4096), dim3(256), 0, stream>>>(Wa, W_hh, ba, b_hh, wcatbf, bcat);
  build_g3_kernel<<<dim3(3072), dim3(256), 0, stream>>>(W_ih, wihc3bf, 1024, 512);
  build_g3_kernel<<<dim3(3072), dim3(256), 0, stream>>>(W_hh, whh3bf, 512, 0);
  build_wihe_kernel<<<dim3(3072), dim3(256), 0, stream>>>(W_ih, wihebf);
  cvt_f2b_kernel<<<dim3(256), dim3(256), 0, stream>>>(Ua, uabf, (long long)HH*HH);
  cvt_f2b_kernel<<<dim3(2048), dim3(256), 0, stream>>>(enc, encbf, (long long)BB*SS*HH);
  build_embbf_kernel<<<dim3(4096), dim3(256), 0, stream>>>(emb, tgt, embbf);
  hinit_kernel<<<dim3(128), dim3(256), 0, stream>>>(eh, hbf0, h320);

  // Uk (bf16 out) and GiEmb (bf16 out) via MFMA
  mfma_nt<1><<<dim3(4, 32), dim3(256), 0, stream>>>(encbf, uabf, bu, (void*)ukbf, (long long)HH);
  mfma_nt<1><<<dim3(12, 32), dim3(256), 0, stream>>>(embbf, wihebf, b_ih, (void*)giembbf, (long long)H3);

  // q(0) = h0 @ Wa^T (no bias; attn adds bcat)
  qinit_mfma<<<dim3(4), dim3(256), 0, stream>>>(hbf0, wcatbf, qbuf);

  // ---- recurrence: 2 launches/step ----
  for (int t = 0; t < TT; ++t) {
    const unsigned short* hr  = (t & 1) ? hbf1 : hbf0;
    const float*          h32r = (t & 1) ? h321 : h320;
    unsigned short*       hw  = (t & 1) ? hbf0 : hbf1;
    float*                h32w = (t & 1) ? h320 : h321;
    attn_kernel<<<dim3(64), dim3(512), 0, stream>>>(t, (t == 0) ? 1 : 0, qbuf, qPart,
        bcat, ukbf, encbf, Va, bvp, ctxbf, attn_out);
    gates_qgh_mfma<<<dim3(16), dim3(256), 0, stream>>>(t, (t == TT - 1) ? 1 : 0,
        hr, ctxbf, wihc3bf, whh3bf, wcatbf, bcat, giembbf,
        h32r, h32w, hw, hsall, out_ht, qPart);
  }

  // ---- output projection + log-softmax ----
  cvt_f2b_kernel<<<dim3(16000), dim3(256), 0, stream>>>(W_out, wbf, (long long)VV*HH);
  mfma_nt<0><<<dim3(250, 32), dim3(256), 0, stream>>>(hsall, wbf, b_out, (void*)out, (long long)VV);
  logsoftmax_kernel<<<dim3(4096), dim3(1024), 0, stream>>>(out);
}